// Round 2
// 79.778 us; speedup vs baseline: 1.0243x; 1.0243x over previous
//
#include <hip/hip_runtime.h>
#include <math.h>

// AttentionContextEncoder on MI355X — R8 (resubmit; prior round was an infra
// failure, not a kernel verdict): LDS-diet restructure.
// Theory: R7 was LDS-pipe-bound (~590 DS wave-ops/thread, 8-way conflicts in
// the moment pass, 13 scalar per-h reads per ni).  R8:
//   * sPT2/sAd2 deleted — p^2 / d^2 MFMA frags built in registers via
//     v_cvt_pk_bf16_f32 (square-on-unpack).           (-27.6 KB LDS, -96 DS)
//   * per-h epilogue scalars packed into float4 tables EA/EB/EC/EQ
//     (13 scalar reads/ni -> 4 ds_read_b128).
//   * se[i] / sD1..3[i] hoisted out of the ni loop.
//   * phase-E moments: all 4 waves, +2h column rotation -> conflict-free.
//   * phase-B j = 4*jj+part -> broadcast se reads, fewer write conflicts.
//   * LDS 63.6 -> 38.3 KB, __launch_bounds__(256,3).

#define NUM_ENT 64
#define HALF    128
#define BATCH   512
#define ROWA    72     // ushort stride (144 B = 9*16: aligned, bank-staggered)
#define ROWP    72

typedef short s16x8 __attribute__((ext_vector_type(8)));
typedef float f32x4 __attribute__((ext_vector_type(4)));

__device__ __forceinline__ unsigned short f2bf(float f) {
    union { float f; unsigned u; } c; c.f = f;
    return (unsigned short)((c.u + 0x7fffu + ((c.u >> 16) & 1u)) >> 16);
}
__device__ __forceinline__ float bf2f(unsigned short s) {
    union { unsigned u; float f; } c; c.u = ((unsigned)s) << 16;
    return c.f;
}
__device__ __forceinline__ float tanh5(float x) {
    float x2 = x * x;
    return x * fmaf(x2, fmaf(x2, 0.13333334f, -0.33333334f), 1.0f);
}
__device__ __forceinline__ unsigned cvt_pk_bf16(float lo, float hi) {
    unsigned r;
    asm("v_cvt_pk_bf16_f32 %0, %1, %2" : "=v"(r) : "v"(lo), "v"(hi));
    return r;
}
// square each bf16 element of a frag, in registers (replaces sPT2/sAd2 LDS)
__device__ __forceinline__ s16x8 sqr_frag(s16x8 v) {
    union { s16x8 s; unsigned u[4]; } in, out;
    in.s = v;
    #pragma unroll
    for (int m = 0; m < 4; ++m) {
        unsigned w = in.u[m];
        float lo = __uint_as_float(w << 16);
        float hi = __uint_as_float(w & 0xffff0000u);
        out.u[m] = cvt_pk_bf16(lo * lo, hi * hi);
    }
    return out.s;
}

__global__ __launch_bounds__(256, 3) void fused_enc(
    const float* __restrict__ ctx, const float* __restrict__ Wp,
    const float* __restrict__ bp,  const float* __restrict__ Wr,
    const float* __restrict__ br,  float* __restrict__ out)
{
    __shared__ __align__(16) float  se[NUM_ENT * 4];        // entities [n][4]
    __shared__ __align__(16) float4 sEA[HALF];              // w0..w3
    __shared__ __align__(16) float4 sEQ[HALF];              // q0..q3
    __shared__ __align__(16) float4 sEB[HALF];              // P1, p2h, p3h, bq
    __shared__ __align__(16) float4 sEC[HALF];              // w4, w4^2, w4^3, bb
    __shared__ float sw4[HALF], sbb[HALF], sbp[HALF];
    __shared__ __align__(16) unsigned short sAd[NUM_ENT][ROWA];  // d  bf16
    __shared__ __align__(16) unsigned short sPT[HALF][ROWP];     // P^T bf16
    __shared__ float sD1[NUM_ENT], sD2[NUM_ENT], sD3[NUM_ENT];
    __shared__ float sEsum[4];

    const int t    = threadIdx.x;
    const int b    = blockIdx.x;
    const int lane = t & 63;
    const int wv   = t >> 6;

    // ---- stage: entity column b + packed weight tables ----
    se[t] = ctx[(size_t)t * BATCH + b];
    if (t < HALF) {
        sEA[t] = make_float4(Wr[t], Wr[HALF + t], Wr[2*HALF + t], Wr[3*HALF + t]);
        sEQ[t] = make_float4(Wp[t], Wp[HALF + t], Wp[2*HALF + t], Wp[3*HALF + t]);
        sw4[t] = Wr[4*HALF + t];
        sbb[t] = br[t];
        sbp[t] = bp[t];
    }
    __syncthreads();

    // ---- phase B: dists (bf16) + per-i moments D1,D2,D3 (fp32 exact) ----
    {
        const int i = t >> 2, part = t & 3;
        const float eix = se[i*4 + 0], eiy = se[i*4 + 1];
        float d1s = 0.f, d2s = 0.f, d3s = 0.f;
        #pragma unroll
        for (int jj = 0; jj < 16; ++jj) {
            int j = jj * 4 + part;            // broadcast se reads, low-conflict
            float dx = eix - se[j*4 + 0], dy = eiy - se[j*4 + 1];
            float d2 = fmaf(dx, dx, dy * dy);
            float d  = sqrtf(d2);             // exact 0 at j==i
            sAd[i][j] = f2bf(d);
            d1s += d; d2s += d2; d3s = fmaf(d, d2, d3s);
        }
        d1s += __shfl_xor(d1s, 1); d1s += __shfl_xor(d1s, 2);
        d2s += __shfl_xor(d2s, 1); d2s += __shfl_xor(d2s, 2);
        d3s += __shfl_xor(d3s, 1); d3s += __shfl_xor(d3s, 2);
        if (part == 0) { sD1[i] = d1s; sD2[i] = d2s; sD3[i] = d3s; }
    }

    // ---- phase C: Esum = sum_j e_j (exact P1 source) ----
    if (t < 64) {
        float4 e = ((const float4*)se)[t];
        float ex = e.x, ey = e.y, ez = e.z, ew = e.w;
        #pragma unroll
        for (int s = 1; s < 64; s <<= 1) {
            ex += __shfl_xor(ex, s); ey += __shfl_xor(ey, s);
            ez += __shfl_xor(ez, s); ew += __shfl_xor(ew, s);
        }
        if (t == 0) { sEsum[0]=ex; sEsum[1]=ey; sEsum[2]=ez; sEsum[3]=ew; }
    }

    // ---- phase D: P^T bf16 (wave wv: h in [32wv,32wv+32), lane = j) ----
    {
        const float4 ej = ((const float4*)se)[lane];
        #pragma unroll 4
        for (int hh = 0; hh < 32; ++hh) {
            int h = wv * 32 + hh;             // wave-uniform
            float4 w = sEA[h];
            float p = fmaf(ej.x, w.x, fmaf(ej.y, w.y, fmaf(ej.z, w.z, ej.w * w.w)));
            sPT[h][lane] = f2bf(p);
        }
    }
    __syncthreads();

    // ---- phase E: per-h moments + packed epilogue tables (all 4 waves) ----
    {
        const int h = t >> 1, jh = t & 1;     // 2 lanes per h, 32 j each
        float s2 = 0.f, s3m = 0.f;
        #pragma unroll 8
        for (int k = 0; k < 32; ++k) {
            int c = (jh * 32 + k + 2 * h) & 63;   // rotation -> conflict-free
            float p  = bf2f(sPT[h][c]);
            float p2 = p * p;
            s2 += p2; s3m = fmaf(p, p2, s3m);
        }
        s2  += __shfl_xor(s2, 1);
        s3m += __shfl_xor(s3m, 1);
        if (jh == 0) {
            float4 w = sEA[h];
            float P1 = fmaf(sEsum[0], w.x, fmaf(sEsum[1], w.y,
                       fmaf(sEsum[2], w.z, sEsum[3] * w.w)));
            float w4 = sw4[h], bb = sbb[h];
            float w42 = w4 * w4;
            sEB[h] = make_float4(P1, s2, s3m, sbp[h]);
            sEC[h] = make_float4(w4, w42, w42 * w4, bb);
        }
    }
    __syncthreads();

    // ---- phase F: MFMA moments + fused epilogue ----
    {
        const int n15 = lane & 15, quad = lane >> 4;
        const int mrow = wv * 16 + n15;       // A-operand row (i)

        s16x8 afd0 = *(const s16x8*)&sAd[mrow][quad * 8];
        s16x8 afd1 = *(const s16x8*)&sAd[mrow][32 + quad * 8];
        s16x8 afq0 = sqr_frag(afd0);          // d^2 frags in registers
        s16x8 afq1 = sqr_frag(afd1);

        const int i0 = wv * 16 + quad * 4;    // C-layout row base
        float4 eh[4]; float D1r[4], D2r[4], D3r[4];
        #pragma unroll
        for (int r = 0; r < 4; ++r) {
            eh[r]  = ((const float4*)se)[i0 + r];
            D1r[r] = sD1[i0 + r]; D2r[r] = sD2[i0 + r]; D3r[r] = sD3[i0 + r];
        }
        float* outb = out + (size_t)(b * NUM_ENT + i0) * (2 * HALF);
        const float C3 = -0.33333334f;

        #pragma unroll 1
        for (int ni = 0; ni < 8; ++ni) {
            const int h = ni * 16 + n15;
            s16x8 bp0 = *(const s16x8*)&sPT[h][quad * 8];
            s16x8 bp1 = *(const s16x8*)&sPT[h][32 + quad * 8];
            s16x8 bq0 = sqr_frag(bp0);        // p^2 frags in registers
            s16x8 bq1 = sqr_frag(bp1);

            f32x4 Ma = {0.f,0.f,0.f,0.f}, Mb = {0.f,0.f,0.f,0.f},
                  Mc = {0.f,0.f,0.f,0.f};
            Ma = __builtin_amdgcn_mfma_f32_16x16x32_bf16(afd0, bp0, Ma, 0,0,0);
            Ma = __builtin_amdgcn_mfma_f32_16x16x32_bf16(afd1, bp1, Ma, 0,0,0);
            Mb = __builtin_amdgcn_mfma_f32_16x16x32_bf16(afd0, bq0, Mb, 0,0,0);
            Mb = __builtin_amdgcn_mfma_f32_16x16x32_bf16(afd1, bq1, Mb, 0,0,0);
            Mc = __builtin_amdgcn_mfma_f32_16x16x32_bf16(afq0, bp0, Mc, 0,0,0);
            Mc = __builtin_amdgcn_mfma_f32_16x16x32_bf16(afq1, bp1, Mc, 0,0,0);

            const float4 EA = sEA[h], EB = sEB[h], EC = sEC[h], EQ = sEQ[h];
            const float P1 = EB.x, p2h = EB.y, p3h = EB.z, bq = EB.w;
            const float w4 = EC.x, w42 = EC.y, w43 = EC.z, bb = EC.w;
            const float diag = fmaf(C3, bb * (bb * bb), bb);   // tanh3(x_ii=bb)

            #pragma unroll
            for (int r = 0; r < 4; ++r) {
                const float4 e = eh[r];
                float pi = fmaf(e.x, EA.x, fmaf(e.y, EA.y,
                           fmaf(e.z, EA.z, e.w * EA.w)));
                float a  = pi + bb;
                float a2 = a * a, a3 = a2 * a;
                float s3 = 64.0f * a3 - 3.0f * a2 * P1 + 3.0f * a * p2h - p3h
                         + w4  * fmaf(3.0f * a2, D1r[r],
                                      fmaf(-6.0f * a, Ma[r], 3.0f * Mb[r]))
                         + w42 * fmaf(3.0f * a, D2r[r], -3.0f * Mc[r])
                         + w43 * D3r[r];
                float lin = fmaf(64.0f, a, -P1) + w4 * D1r[r];
                float rel = fmaf(C3, s3, lin) - diag;
                float xp  = fmaf(e.x, EQ.x, fmaf(e.y, EQ.y,
                            fmaf(e.z, EQ.z, fmaf(e.w, EQ.w, bq))));
                float* o = outb + r * (2 * HALF);
                o[h]        = tanh5(xp);
                o[HALF + h] = rel;
            }
        }
    }
}

extern "C" void kernel_launch(void* const* d_in, const int* in_sizes, int n_in,
                              void* d_out, int out_size, void* d_ws, size_t ws_size,
                              hipStream_t stream) {
    const float* ctx = (const float*)d_in[0];
    const float* Wp  = (const float*)d_in[1];
    const float* bp  = (const float*)d_in[2];
    const float* Wr  = (const float*)d_in[3];
    const float* br  = (const float*)d_in[4];
    float* out = (float*)d_out;

    fused_enc<<<dim3(BATCH), dim3(256), 0, stream>>>(ctx, Wp, bp, Wr, br, out);
}